// Round 6
// baseline (722.248 us; speedup 1.0000x reference)
//
#include <hip/hip_runtime.h>

constexpr int B_ = 8;
constexpr int N_ = 2048;
constexpr int K_ = 20;
constexpr float SLOPE_ = 0.2f;

typedef __attribute__((ext_vector_type(8))) short bf16x8;
typedef __attribute__((ext_vector_type(4))) float f32x4;

__device__ __forceinline__ float lrelu(float v) { return v > 0.0f ? v : SLOPE_ * v; }

__device__ __forceinline__ void async16(const void* g, void* l) {
  __builtin_amdgcn_global_load_lds((const __attribute__((address_space(1))) unsigned int*)g,
                                   (__attribute__((address_space(3))) unsigned int*)l, 16, 0, 0);
}

__device__ __forceinline__ unsigned long long shflx64(unsigned long long v, int m) {
  return __shfl_xor(v, m, 64);
}

// Build Wp[2O x C]: rows [0,O) = Wd = W[:, :C]; rows [O,2O) = Wc - Wd
__global__ void prep_wp(const float* __restrict__ W, float* __restrict__ Wp, int O, int C) {
  int i = blockIdx.x * 256 + threadIdx.x;
  if (i >= 2 * O * C) return;
  int o = i / C, c = i - o * C;
  if (o < O)
    Wp[i] = W[o * 2 * C + c];
  else
    Wp[i] = W[(o - O) * 2 * C + C + c] - W[(o - O) * 2 * C + c];
}

// fp32 -> bf16 (RNE), vectorized x4
__global__ void cvt_bf16(const float4* __restrict__ src, ushort4* __restrict__ dst, int n4) {
  int i = blockIdx.x * 256 + threadIdx.x;
  if (i >= n4) return;
  float4 v = src[i];
  ushort4 o;
  unsigned u;
  u = __float_as_uint(v.x); u += 0x7fff + ((u >> 16) & 1); o.x = u >> 16;
  u = __float_as_uint(v.y); u += 0x7fff + ((u >> 16) & 1); o.y = u >> 16;
  u = __float_as_uint(v.z); u += 0x7fff + ((u >> 16) & 1); o.z = u >> 16;
  u = __float_as_uint(v.w); u += 0x7fff + ((u >> 16) & 1); o.w = u >> 16;
  dst[i] = o;
}

// norms of x rows (C=3)
__global__ void norms_x(const float* __restrict__ x, float* __restrict__ xx) {
  int i = blockIdx.x * 256 + threadIdx.x;
  if (i >= B_ * N_) return;
  const float* p = x + (size_t)i * 3;
  xx[i] = p[0] * p[0] + p[1] * p[1] + p[2] * p[2];
}

// Transpose features: hin rows (stride `stride`, C real cols) -> xT[b][CP][N_],
// zero-padding cols C..CP. LDS tile 64 rows x CP, both sides coalesced.
template <int C, int CP>
__global__ __launch_bounds__(256) void transpose_feat(const float* __restrict__ hin, int stride,
                                                      float* __restrict__ xT) {
  __shared__ float ts[64][CP + 1];
  const int b = blockIdx.y, n0 = blockIdx.x * 64;
  for (int i = threadIdx.x; i < 64 * C; i += 256) {
    int n = i / C, c = i - n * C;
    ts[n][c] = hin[(size_t)(b * N_ + n0 + n) * stride + c];
  }
  if (CP > C)
    for (int i = threadIdx.x; i < 64 * (CP - C); i += 256) {
      int n = i / (CP - C), c = C + (i - n * (CP - C));
      ts[n][c] = 0.0f;
    }
  __syncthreads();
  for (int i = threadIdx.x; i < 64 * CP; i += 256) {
    int c = i >> 6, n = i & 63;
    xT[((size_t)b * CP + c) * N_ + n0 + n] = ts[n][c];
  }
}

// kNN v5: 8 queries/block, 256 threads. Candidates staged coalesced from xT via
// global_load_lds (k-slices xs[4][2048]); query values read with WAVE-UNIFORM
// addresses directly from hin -> compiler scalarizes to s_load (constant cache),
// so the LDS pipe only serves the 8 lane-varying xs reads per k (FMA-bound).
// d2 = max(xxm + xxq - 2*dot, 0). Selection: threshold (20th-smallest lane-min via
// bitonic) + ballot-compact + u64 bitonic sort; exact-pop fallback if cnt > 64.
template <int C, int CP>
__global__ __launch_bounds__(256) void knn_kernel(const float* __restrict__ hin, int stride,
                                                  const float* __restrict__ xT,
                                                  const float* __restrict__ xx,
                                                  int* __restrict__ idxo) {
  const int b = blockIdx.y;
  const int q0 = blockIdx.x * 8;
  const int tid = threadIdx.x;
  const int w = tid >> 6, lane = tid & 63;
  const int bN = b * N_;

  __shared__ float xs[4][2048];  // k-slice staging; reused as d2s[8][1024]
  __shared__ unsigned long long cbuf[4][64];

  const float* qrow0 = hin + (size_t)(bN + q0) * stride;  // uniform

  float acc[8][8] = {};  // [q][mi], m = tid + 256*mi
  const float* srcb = xT + (size_t)b * CP * N_;
  float* xsf = &xs[0][0];

  for (int c0 = 0; c0 < CP; c0 += 4) {
    __syncthreads();  // previous stage's xs reads done
#pragma unroll
    for (int j = 0; j < 8; j++) {
      const int f0 = (w * 8 + j) * 256;
      async16(srcb + (size_t)c0 * N_ + f0 + lane * 4, xsf + f0);
    }
    __syncthreads();  // drains vmcnt -> xs ready
#pragma unroll
    for (int kc = 0; kc < 4; kc++) {
      const int c = c0 + kc;
      float xv[8];
#pragma unroll
      for (int mi = 0; mi < 8; mi++) xv[mi] = xs[kc][tid + 256 * mi];
#pragma unroll
      for (int q = 0; q < 8; q++) {
        float qv;
        if constexpr (CP == C)
          qv = qrow0[(size_t)q * stride + c];
        else
          qv = (c < C) ? qrow0[(size_t)q * stride + c] : 0.0f;
#pragma unroll
        for (int mi = 0; mi < 8; mi++) acc[q][mi] = fmaf(xv[mi], qv, acc[q][mi]);
      }
    }
  }

  float xxm[8];
#pragma unroll
  for (int mi = 0; mi < 8; mi++) xxm[mi] = xx[bN + tid + 256 * mi];
  float qnr[8];
#pragma unroll
  for (int q = 0; q < 8; q++) qnr[q] = xx[bN + q0 + q];  // uniform -> s_load
#pragma unroll
  for (int q = 0; q < 8; q++)
#pragma unroll
    for (int mi = 0; mi < 8; mi++)
      acc[q][mi] = fmaxf(fmaf(-2.0f, acc[q][mi], xxm[mi] + qnr[q]), 0.0f);

  // exchange: wave w takes queries 2w, 2w+1 with all 2048 candidates in regs
  float (*d2s)[1024] = (float(*)[1024])xsf;
  float r2[2][32];  // r2[s][i]: m = (i>>4)*1024 + (i&15)*64 + lane
#pragma unroll
  for (int jc = 0; jc < 2; jc++) {
    __syncthreads();
#pragma unroll
    for (int q = 0; q < 8; q++)
#pragma unroll
      for (int mi = 0; mi < 4; mi++) d2s[q][tid + 256 * mi] = acc[q][jc * 4 + mi];
    __syncthreads();
#pragma unroll
    for (int s = 0; s < 2; s++)
#pragma unroll
      for (int t = 0; t < 16; t++) r2[s][16 * jc + t] = d2s[2 * w + s][t * 64 + lane];
  }

  const float INF = __int_as_float(0x7f800000);

#pragma unroll
  for (int s = 0; s < 2; s++) {
    const int q = 2 * w + s;
    int* outp = idxo + (size_t)(bN + q0 + q) * K_;

    // ---- threshold: T = 20th-smallest per-lane min ----
    float lmin = r2[s][0];
#pragma unroll
    for (int i = 1; i < 32; i++) lmin = fminf(lmin, r2[s][i]);
    float sv = lmin;
#pragma unroll
    for (int k = 2; k <= 64; k <<= 1)
#pragma unroll
      for (int j = k >> 1; j > 0; j >>= 1) {
        float p = __shfl_xor(sv, j, 64);
        bool takeMax = ((lane & j) != 0) == ((lane & k) == 0);
        sv = takeMax ? fmaxf(sv, p) : fminf(sv, p);
      }
    float T = __shfl(sv, 19, 64);

    // ---- count + compact candidates <= T ----
    unsigned long long* cb = cbuf[w];
    unsigned cnt = 0;
#pragma unroll
    for (int i = 0; i < 32; i++) {
      const int mb = (i >> 4) * 1024 + (i & 15) * 64;
      bool pred = r2[s][i] <= T;
      unsigned long long mk = __ballot(pred);
      if (mk) {
        int off = __popcll(mk & ((1ull << lane) - 1ull));
        unsigned pos = cnt + (unsigned)off;
        if (pred && pos < 64)
          cb[pos] = ((unsigned long long)__float_as_uint(r2[s][i]) << 32) | (unsigned)(mb + lane);
        cnt += (unsigned)__popcll(mk);
      }
    }

    if (cnt <= 64) {
      unsigned long long v = (lane < (int)cnt) ? cb[lane] : ~0ull;
#pragma unroll
      for (int k = 2; k <= 64; k <<= 1)
#pragma unroll
        for (int j = k >> 1; j > 0; j >>= 1) {
          unsigned long long p = shflx64(v, j);
          bool takeMax = ((lane & j) != 0) == ((lane & k) == 0);
          bool lt = v < p;
          v = (takeMax == lt) ? p : v;
        }
      if (lane < K_) outp[lane] = (int)(unsigned)(v & 0xffffffffull);
    } else {
      for (int t = 0; t < K_; t++) {
        unsigned long long loc = ~0ull;
#pragma unroll
        for (int i = 0; i < 32; i++) {
          const int mb = (i >> 4) * 1024 + (i & 15) * 64;
          unsigned long long u =
              ((unsigned long long)__float_as_uint(r2[s][i]) << 32) | (unsigned)(mb + lane);
          loc = u < loc ? u : loc;
        }
#pragma unroll
        for (int off = 32; off > 0; off >>= 1) {
          unsigned long long vv = shflx64(loc, off);
          loc = vv < loc ? vv : loc;
        }
        const int mwin = (int)(unsigned)(loc & 0xffffffffull);
        if (lane == 0) outp[t] = mwin;
#pragma unroll
        for (int i = 0; i < 32; i++) {
          const int mb = (i >> 4) * 1024 + (i & 15) * 64;
          if (mb + lane == mwin) r2[s][i] = INF;
        }
      }
    }
  }
}

// P[row, o'] = sum_c h[row, c] * Wp[o', c]   for o' in [0, 2O). OPT outputs/thread
// (o, o+T, ...) raises FMA : ds_read ratio; blockDim = O2/OPT.
template <int C, int O2, int OPT>
__global__ void proj_kernel(const float* __restrict__ hin, int stride,
                            const float* __restrict__ Wp, float* __restrict__ P) {
  constexpr int T = O2 / OPT;
  const int nt = blockIdx.x * 16;
  const int o = threadIdx.x;
  __shared__ float hs[16][C];
  for (int i = threadIdx.x; i < 16 * C; i += T) {
    int r = i / C, c = i - r * C;
    hs[r][c] = hin[(size_t)(nt + r) * stride + c];
  }
  __syncthreads();
  float acc[OPT][16] = {};
  const float* wr[OPT];
#pragma unroll
  for (int u = 0; u < OPT; u++) wr[u] = Wp + (size_t)(o + u * T) * C;
  if constexpr (C % 4 == 0) {
    for (int cg = 0; cg < C; cg += 4) {
      float4 wv[OPT];
#pragma unroll
      for (int u = 0; u < OPT; u++) wv[u] = *(const float4*)(wr[u] + cg);
#pragma unroll
      for (int t = 0; t < 16; t++) {
        float4 h = *(const float4*)(&hs[t][cg]);
#pragma unroll
        for (int u = 0; u < OPT; u++)
          acc[u][t] += wv[u].x * h.x + wv[u].y * h.y + wv[u].z * h.z + wv[u].w * h.w;
      }
    }
  } else {
    for (int c = 0; c < C; c++) {
      float wv[OPT];
#pragma unroll
      for (int u = 0; u < OPT; u++) wv[u] = wr[u][c];
#pragma unroll
      for (int t = 0; t < 16; t++) {
        float h = hs[t][c];
#pragma unroll
        for (int u = 0; u < OPT; u++) acc[u][t] += wv[u] * h;
      }
    }
  }
#pragma unroll
  for (int t = 0; t < 16; t++)
#pragma unroll
    for (int u = 0; u < OPT; u++) P[(size_t)(nt + t) * O2 + o + u * T] = acc[u][t];
}

// h_out[row, o] = lrelu( max_k P[nbr_k, o] + P[row, O + o] + bias[o] ); also emits
// row norm (over this layer's O outputs) for the next layer's kNN.
template <int O>
__global__ void combine_kernel(const float* __restrict__ P, const int* __restrict__ idxo,
                               const float* __restrict__ bias, float* __restrict__ hout,
                               float* __restrict__ xxo) {
  const int row = blockIdx.x;
  const int o = threadIdx.x;
  __shared__ int idxs[K_];
  __shared__ float ps[4];
  if (o < K_) idxs[o] = idxo[(size_t)row * K_ + o];
  __syncthreads();
  const int base_row = (row >> 11) << 11;
  float g = -3.4e38f;
#pragma unroll
  for (int k = 0; k < K_; k++) {
    float v = P[(size_t)(base_row + idxs[k]) * (2 * O) + o];
    g = fmaxf(g, v);
  }
  float ba = P[(size_t)row * (2 * O) + O + o];
  float val = lrelu(g + ba + bias[o]);
  hout[(size_t)row * 512 + o] = val;
  if (xxo) {
    float sq = val * val;
#pragma unroll
    for (int off = 32; off > 0; off >>= 1) sq += __shfl_xor(sq, off, 64);
    if ((o & 63) == 0) ps[o >> 6] = sq;
    __syncthreads();
    if (o == 0) {
      float t = ps[0];
#pragma unroll
      for (int u = 1; u < O / 64; u++) t += ps[u];
      xxo[row] = t;
    }
  }
}

// Final GEMM: 128x128 tile, BK=32, global_load_lds(16B), 16x16x32 bf16 MFMA,
// epilogue = max over the block's 128 m-rows -> part.
__global__ __launch_bounds__(256) void gemm_final(const unsigned short* __restrict__ A,
                                                  const unsigned short* __restrict__ Bw,
                                                  float* __restrict__ part) {
  const int m0 = blockIdx.x * 128;
  const int n0 = blockIdx.y * 128;
  const int tid = threadIdx.x;
  const int w = tid >> 6, lane = tid & 63;
  const int wm = w & 1, wn = w >> 1;

  __shared__ unsigned short lA[128 * 32];
  __shared__ unsigned short lB[128 * 32];
  __shared__ float ldsred[2][128];

  const int r0 = (w * 2 + 0) * 16 + (lane >> 2);
  const int r1 = (w * 2 + 1) * 16 + (lane >> 2);
  const int ks = (lane & 3) * 8;
  const unsigned short* a0 = A + (size_t)(m0 + r0) * 512 + ks;
  const unsigned short* a1 = A + (size_t)(m0 + r1) * 512 + ks;
  const unsigned short* b0 = Bw + (size_t)(n0 + r0) * 512 + ks;
  const unsigned short* b1 = Bw + (size_t)(n0 + r1) * 512 + ks;
  unsigned short* lA0 = lA + (w * 2 + 0) * 512;
  unsigned short* lA1 = lA + (w * 2 + 1) * 512;
  unsigned short* lB0 = lB + (w * 2 + 0) * 512;
  unsigned short* lB1 = lB + (w * 2 + 1) * 512;

  f32x4 acc[4][4] = {};
  const int ka = (lane >> 4) * 8;

  for (int k0 = 0; k0 < 512; k0 += 32) {
    __syncthreads();
    async16(a0 + k0, lA0);
    async16(a1 + k0, lA1);
    async16(b0 + k0, lB0);
    async16(b1 + k0, lB1);
    __syncthreads();
    bf16x8 af[4], bfr[4];
#pragma unroll
    for (int mt = 0; mt < 4; mt++)
      af[mt] = *(const bf16x8*)&lA[(wm * 64 + mt * 16 + (lane & 15)) * 32 + ka];
#pragma unroll
    for (int nt = 0; nt < 4; nt++)
      bfr[nt] = *(const bf16x8*)&lB[(wn * 64 + nt * 16 + (lane & 15)) * 32 + ka];
#pragma unroll
    for (int mt = 0; mt < 4; mt++)
#pragma unroll
      for (int nt = 0; nt < 4; nt++)
        acc[mt][nt] = __builtin_amdgcn_mfma_f32_16x16x32_bf16(af[mt], bfr[nt], acc[mt][nt], 0, 0, 0);
  }

#pragma unroll
  for (int nt = 0; nt < 4; nt++) {
    float v = -3.4e38f;
#pragma unroll
    for (int mt = 0; mt < 4; mt++)
#pragma unroll
      for (int r = 0; r < 4; r++) v = fmaxf(v, acc[mt][nt][r]);
    v = fmaxf(v, __shfl_xor(v, 16, 64));
    v = fmaxf(v, __shfl_xor(v, 32, 64));
    if (lane < 16) ldsred[wm][wn * 64 + nt * 16 + lane] = v;
  }
  __syncthreads();
  if (tid < 128) {
    float v = fmaxf(ldsred[0][tid], ldsred[1][tid]);
    const int b = blockIdx.x >> 4, s5 = blockIdx.x & 15;
    part[(size_t)(b * 16 + s5) * 1024 + n0 + tid] = v;
  }
}

__global__ void final_reduce(const float* __restrict__ part, const float* __restrict__ bf,
                             float* __restrict__ out) {
  int i = blockIdx.x * 256 + threadIdx.x;
  if (i >= B_ * 1024) return;
  int b = i >> 10, o = i & 1023;
  float m = -3.4e38f;
  for (int s = 0; s < 16; s++) m = fmaxf(m, part[(size_t)(b * 16 + s) * 1024 + o]);
  out[i] = lrelu(m + bf[o]);
}

extern "C" void kernel_launch(void* const* d_in, const int* in_sizes, int n_in, void* d_out,
                              int out_size, void* d_ws, size_t ws_size, hipStream_t stream) {
  (void)in_sizes; (void)n_in; (void)out_size; (void)ws_size;
  const float* x = (const float*)d_in[0];
  const float* W1 = (const float*)d_in[1];
  const float* b1 = (const float*)d_in[2];
  const float* W2 = (const float*)d_in[3];
  const float* b2 = (const float*)d_in[4];
  const float* W3 = (const float*)d_in[5];
  const float* b3 = (const float*)d_in[6];
  const float* W4 = (const float*)d_in[7];
  const float* b4 = (const float*)d_in[8];
  const float* Wf = (const float*)d_in[9];
  const float* bf = (const float*)d_in[10];

  float* ws = (float*)d_ws;
  float* hcat = ws;                               // B*N*512 floats (32 MB)
  float* P = hcat + (size_t)B_ * N_ * 512;        // B*N*512 floats (32 MB)
  int* idx = (int*)(P + (size_t)B_ * N_ * 512);   // B*N*20 ints
  float* Wp = (float*)(idx + (size_t)B_ * N_ * K_);
  float* part = Wp + 512 * 128;                   // 8*16*1024 floats
  float* xxb = part + 8 * 16 * 1024;              // B*N floats (row norms)
  float* out = (float*)d_out;
  float* xT = P;                                  // alias P: xT dead before proj writes P
  unsigned short* hcat_bf = (unsigned short*)P;   // alias P (dead after layer-4)
  unsigned short* Wf_bf = hcat_bf + (size_t)B_ * N_ * 512;

  dim3 knng(N_ / 8, B_);
  dim3 trg(N_ / 64, B_);

  // Layer 1: C=3 -> O=64
  prep_wp<<<(2 * 64 * 3 + 255) / 256, 256, 0, stream>>>(W1, Wp, 64, 3);
  norms_x<<<(B_ * N_ + 255) / 256, 256, 0, stream>>>(x, xxb);
  transpose_feat<3, 4><<<trg, 256, 0, stream>>>(x, 3, xT);
  knn_kernel<3, 4><<<knng, 256, 0, stream>>>(x, 3, xT, xxb, idx);
  proj_kernel<3, 128, 1><<<dim3(B_ * N_ / 16), 128, 0, stream>>>(x, 3, Wp, P);
  combine_kernel<64><<<B_ * N_, 64, 0, stream>>>(P, idx, b1, hcat + 0, xxb);

  // Layer 2: C=64 -> O=64
  prep_wp<<<(2 * 64 * 64 + 255) / 256, 256, 0, stream>>>(W2, Wp, 64, 64);
  transpose_feat<64, 64><<<trg, 256, 0, stream>>>(hcat + 0, 512, xT);
  knn_kernel<64, 64><<<knng, 256, 0, stream>>>(hcat + 0, 512, xT, xxb, idx);
  proj_kernel<64, 128, 1><<<dim3(B_ * N_ / 16), 128, 0, stream>>>(hcat + 0, 512, Wp, P);
  combine_kernel<64><<<B_ * N_, 64, 0, stream>>>(P, idx, b2, hcat + 64, xxb);

  // Layer 3: C=64 -> O=128
  prep_wp<<<(2 * 128 * 64 + 255) / 256, 256, 0, stream>>>(W3, Wp, 128, 64);
  transpose_feat<64, 64><<<trg, 256, 0, stream>>>(hcat + 64, 512, xT);
  knn_kernel<64, 64><<<knng, 256, 0, stream>>>(hcat + 64, 512, xT, xxb, idx);
  proj_kernel<64, 256, 2><<<dim3(B_ * N_ / 16), 128, 0, stream>>>(hcat + 64, 512, Wp, P);
  combine_kernel<128><<<B_ * N_, 128, 0, stream>>>(P, idx, b3, hcat + 128, xxb);

  // Layer 4: C=128 -> O=256 (no norms needed afterwards)
  prep_wp<<<(2 * 256 * 128 + 255) / 256, 256, 0, stream>>>(W4, Wp, 256, 128);
  transpose_feat<128, 128><<<trg, 256, 0, stream>>>(hcat + 128, 512, xT);
  knn_kernel<128, 128><<<knng, 256, 0, stream>>>(hcat + 128, 512, xT, xxb, idx);
  proj_kernel<128, 512, 4><<<dim3(B_ * N_ / 16), 128, 0, stream>>>(hcat + 128, 512, Wp, P);
  combine_kernel<256><<<B_ * N_, 256, 0, stream>>>(P, idx, b4, hcat + 256, nullptr);

  // Final 1x1 conv via bf16 MFMA + fused max-over-rows
  cvt_bf16<<<(B_ * N_ * 512 / 4 + 255) / 256, 256, 0, stream>>>(
      (const float4*)hcat, (ushort4*)hcat_bf, B_ * N_ * 512 / 4);
  cvt_bf16<<<(1024 * 512 / 4 + 255) / 256, 256, 0, stream>>>(
      (const float4*)Wf, (ushort4*)Wf_bf, 1024 * 512 / 4);
  gemm_final<<<dim3(128, 8), 256, 0, stream>>>(hcat_bf, Wf_bf, part);
  final_reduce<<<(B_ * 1024 + 255) / 256, 256, 0, stream>>>(part, bf, out);
}

// Round 8
// 647.031 us; speedup vs baseline: 1.1162x; 1.1162x over previous
//
#include <hip/hip_runtime.h>

constexpr int B_ = 8;
constexpr int N_ = 2048;
constexpr int K_ = 20;
constexpr float SLOPE_ = 0.2f;

typedef __attribute__((ext_vector_type(8))) short bf16x8;
typedef __attribute__((ext_vector_type(4))) float f32x4;

__device__ __forceinline__ float lrelu(float v) { return v > 0.0f ? v : SLOPE_ * v; }

__device__ __forceinline__ void async16(const void* g, void* l) {
  __builtin_amdgcn_global_load_lds((const __attribute__((address_space(1))) unsigned int*)g,
                                   (__attribute__((address_space(3))) unsigned int*)l, 16, 0, 0);
}

__device__ __forceinline__ unsigned long long shflx64(unsigned long long v, int m) {
  return __shfl_xor(v, m, 64);
}

// Build Wp[2O x C]: rows [0,O) = Wd = W[:, :C]; rows [O,2O) = Wc - Wd
__global__ void prep_wp(const float* __restrict__ W, float* __restrict__ Wp, int O, int C) {
  int i = blockIdx.x * 256 + threadIdx.x;
  if (i >= 2 * O * C) return;
  int o = i / C, c = i - o * C;
  if (o < O)
    Wp[i] = W[o * 2 * C + c];
  else
    Wp[i] = W[(o - O) * 2 * C + C + c] - W[(o - O) * 2 * C + c];
}

// fp32 -> bf16 (RNE), vectorized x4
__global__ void cvt_bf16(const float4* __restrict__ src, ushort4* __restrict__ dst, int n4) {
  int i = blockIdx.x * 256 + threadIdx.x;
  if (i >= n4) return;
  float4 v = src[i];
  ushort4 o;
  unsigned u;
  u = __float_as_uint(v.x); u += 0x7fff + ((u >> 16) & 1); o.x = u >> 16;
  u = __float_as_uint(v.y); u += 0x7fff + ((u >> 16) & 1); o.y = u >> 16;
  u = __float_as_uint(v.z); u += 0x7fff + ((u >> 16) & 1); o.z = u >> 16;
  u = __float_as_uint(v.w); u += 0x7fff + ((u >> 16) & 1); o.w = u >> 16;
  dst[i] = o;
}

// norms of x rows (C=3)
__global__ void norms_x(const float* __restrict__ x, float* __restrict__ xx) {
  int i = blockIdx.x * 256 + threadIdx.x;
  if (i >= B_ * N_) return;
  const float* p = x + (size_t)i * 3;
  xx[i] = p[0] * p[0] + p[1] * p[1] + p[2] * p[2];
}

// Transpose features: hin rows (stride `stride`, C real cols) -> xT[b][CP][N_],
// zero-padding cols C..CP. LDS tile 64 rows x CP, both sides coalesced.
template <int C, int CP>
__global__ __launch_bounds__(256) void transpose_feat(const float* __restrict__ hin, int stride,
                                                      float* __restrict__ xT) {
  __shared__ float ts[64][CP + 1];
  const int b = blockIdx.y, n0 = blockIdx.x * 64;
  for (int i = threadIdx.x; i < 64 * C; i += 256) {
    int n = i / C, c = i - n * C;
    ts[n][c] = hin[(size_t)(b * N_ + n0 + n) * stride + c];
  }
  if (CP > C)
    for (int i = threadIdx.x; i < 64 * (CP - C); i += 256) {
      int n = i / (CP - C), c = C + (i - n * (CP - C));
      ts[n][c] = 0.0f;
    }
  __syncthreads();
  for (int i = threadIdx.x; i < 64 * CP; i += 256) {
    int c = i >> 6, n = i & 63;
    xT[((size_t)b * CP + c) * N_ + n0 + n] = ts[n][c];
  }
}

// kNN v7: 8 queries/block, 256 threads. Wave-private staging: wave w owns candidates
// m = w*512 + mi*64 + lane, stages k-slices into its private 8 KB LDS region (double
// buffer of 2 k-slices) with NO block barriers in the distance loop. Synchronization
// is asm s_waitcnt vmcnt(N) WITH "memory" clobber (compiler may not move LDS reads
// across — the raw builtin allowed that and raced in R7). Query features are staged
// once into LDS (qfs) so the ONLY vmcnt ops in the loop are the 4 staging loads per
// chunk -> vmcnt(4) exactly means "previous chunk landed". qf read as b64 broadcasts.
// Exchange (4 barriers) gives wave w queries 2w,2w+1 with all 2048 candidates in regs:
// r2[s][i] has m = ((i&15)>>2)*512 + ((i>>4)*4 + (i&3))*64 + lane.
// Selection: threshold (20th-smallest lane-min via bitonic) + ballot-compact + u64
// bitonic sort; exact-pop fallback if cnt > 64. cb aliases the wave's own xs region.
template <int C, int CP>
__global__ __launch_bounds__(256) void knn_kernel(const float* __restrict__ hin, int stride,
                                                  const float* __restrict__ xT,
                                                  const float* __restrict__ xx,
                                                  int* __restrict__ idxo) {
  const int b = blockIdx.y;
  const int q0 = blockIdx.x * 8;
  const int tid = threadIdx.x;
  const int w = tid >> 6, lane = tid & 63;
  const int bN = b * N_;

  __shared__ float xs[4][2048];  // wave w owns xs[w]: 2 buffers x 2 k-slices x 512
  __shared__ float qfs[8][CP];   // query features (zero-padded)

  for (int i = tid; i < 8 * CP; i += 256) {
    int q = i / CP, c = i - q * CP;
    qfs[q][c] = (c < C) ? hin[(size_t)(bN + q0 + q) * stride + c] : 0.0f;
  }

  float acc[8][8] = {};  // [q][mi], m = w*512 + mi*64 + lane
  const float* srcb = xT + (size_t)b * CP * N_ + w * 512;
  float* xsw = &xs[w][0];

  __syncthreads();  // qfs ready (also before first staging into xs)

  // prologue: stage chunk 0 (k-slices 0,1) into buffer 0
  async16(srcb + lane * 4, xsw);
  async16(srcb + 256 + lane * 4, xsw + 256);
  async16(srcb + N_ + lane * 4, xsw + 512);
  async16(srcb + N_ + 256 + lane * 4, xsw + 768);

  constexpr int NCH = CP / 2;
#pragma unroll 2
  for (int ch = 0; ch < NCH; ch++) {
    if (ch + 1 < NCH) {
      const float* s0 = srcb + (size_t)((ch + 1) * 2) * N_;
      float* d = xsw + ((ch + 1) & 1) * 1024;
      async16(s0 + lane * 4, d);
      async16(s0 + 256 + lane * 4, d + 256);
      async16(s0 + N_ + lane * 4, d + 512);
      async16(s0 + N_ + 256 + lane * 4, d + 768);
      asm volatile("s_waitcnt vmcnt(4)" ::: "memory");  // chunk ch landed
    } else {
      asm volatile("s_waitcnt vmcnt(0)" ::: "memory");  // last chunk landed
    }
    const float* buf = xsw + (ch & 1) * 1024;
    float xv0[8], xv1[8];
#pragma unroll
    for (int mi = 0; mi < 8; mi++) xv0[mi] = buf[mi * 64 + lane];
#pragma unroll
    for (int mi = 0; mi < 8; mi++) xv1[mi] = buf[512 + mi * 64 + lane];
#pragma unroll
    for (int q = 0; q < 8; q++) {
      float2 qv = *(const float2*)&qfs[q][ch * 2];  // b64 broadcast
#pragma unroll
      for (int mi = 0; mi < 8; mi++) acc[q][mi] = fmaf(xv0[mi], qv.x, acc[q][mi]);
#pragma unroll
      for (int mi = 0; mi < 8; mi++) acc[q][mi] = fmaf(xv1[mi], qv.y, acc[q][mi]);
    }
  }

  float xxm[8];
#pragma unroll
  for (int mi = 0; mi < 8; mi++) xxm[mi] = xx[bN + w * 512 + mi * 64 + lane];
  float qnr[8];
#pragma unroll
  for (int q = 0; q < 8; q++) qnr[q] = xx[bN + q0 + q];  // uniform -> s_load
#pragma unroll
  for (int q = 0; q < 8; q++)
#pragma unroll
    for (int mi = 0; mi < 8; mi++)
      acc[q][mi] = fmaxf(fmaf(-2.0f, acc[q][mi], xxm[mi] + qnr[q]), 0.0f);

  // exchange: wave w fills column slice [w*256, w*256+256) of every row q (chunk jc
  // holds mi = jc*4+mm); reads only its OWN rows 2w,2w+1 (= its own xs region).
  float (*d2s)[1024] = (float(*)[1024])&xs[0][0];
  float r2[2][32];
#pragma unroll
  for (int jc = 0; jc < 2; jc++) {
    __syncthreads();
#pragma unroll
    for (int q = 0; q < 8; q++)
#pragma unroll
      for (int mm = 0; mm < 4; mm++)
        d2s[q][w * 256 + mm * 64 + lane] = acc[q][jc * 4 + mm];
    __syncthreads();
#pragma unroll
    for (int s = 0; s < 2; s++)
#pragma unroll
      for (int t = 0; t < 16; t++) r2[s][jc * 16 + t] = d2s[2 * w + s][t * 64 + lane];
  }

  const float INF = __int_as_float(0x7f800000);
  // per-wave candidate buffer aliases the wave's own (now dead) xs region
  unsigned long long* cb = (unsigned long long*)&xs[w][0];

#pragma unroll
  for (int s = 0; s < 2; s++) {
    const int q = 2 * w + s;
    int* outp = idxo + (size_t)(bN + q0 + q) * K_;

    // ---- threshold: T = 20th-smallest per-lane min ----
    float lmin = r2[s][0];
#pragma unroll
    for (int i = 1; i < 32; i++) lmin = fminf(lmin, r2[s][i]);
    float sv = lmin;
#pragma unroll
    for (int k = 2; k <= 64; k <<= 1)
#pragma unroll
      for (int j = k >> 1; j > 0; j >>= 1) {
        float p = __shfl_xor(sv, j, 64);
        bool takeMax = ((lane & j) != 0) == ((lane & k) == 0);
        sv = takeMax ? fmaxf(sv, p) : fminf(sv, p);
      }
    float T = __shfl(sv, 19, 64);

    // ---- count + compact candidates <= T ----
    unsigned cnt = 0;
#pragma unroll
    for (int i = 0; i < 32; i++) {
      const int mb = ((i & 15) >> 2) * 512 + ((i >> 4) * 4 + (i & 3)) * 64;
      bool pred = r2[s][i] <= T;
      unsigned long long mk = __ballot(pred);
      if (mk) {
        int off = __popcll(mk & ((1ull << lane) - 1ull));
        unsigned pos = cnt + (unsigned)off;
        if (pred && pos < 64)
          cb[pos] = ((unsigned long long)__float_as_uint(r2[s][i]) << 32) | (unsigned)(mb + lane);
        cnt += (unsigned)__popcll(mk);
      }
    }

    if (cnt <= 64) {
      unsigned long long v = (lane < (int)cnt) ? cb[lane] : ~0ull;
#pragma unroll
      for (int k = 2; k <= 64; k <<= 1)
#pragma unroll
        for (int j = k >> 1; j > 0; j >>= 1) {
          unsigned long long p = shflx64(v, j);
          bool takeMax = ((lane & j) != 0) == ((lane & k) == 0);
          bool lt = v < p;
          v = (takeMax == lt) ? p : v;
        }
      if (lane < K_) outp[lane] = (int)(unsigned)(v & 0xffffffffull);
    } else {
      for (int t = 0; t < K_; t++) {
        unsigned long long loc = ~0ull;
#pragma unroll
        for (int i = 0; i < 32; i++) {
          const int mb = ((i & 15) >> 2) * 512 + ((i >> 4) * 4 + (i & 3)) * 64;
          unsigned long long u =
              ((unsigned long long)__float_as_uint(r2[s][i]) << 32) | (unsigned)(mb + lane);
          loc = u < loc ? u : loc;
        }
#pragma unroll
        for (int off = 32; off > 0; off >>= 1) {
          unsigned long long vv = shflx64(loc, off);
          loc = vv < loc ? vv : loc;
        }
        const int mwin = (int)(unsigned)(loc & 0xffffffffull);
        if (lane == 0) outp[t] = mwin;
#pragma unroll
        for (int i = 0; i < 32; i++) {
          const int mb = ((i & 15) >> 2) * 512 + ((i >> 4) * 4 + (i & 3)) * 64;
          if (mb + lane == mwin) r2[s][i] = INF;
        }
      }
    }
  }
}

// P[row, o'] = sum_c h[row, c] * Wp[o', c]   for o' in [0, 2O)  (R5 version)
template <int C, int O2>
__global__ void proj_kernel(const float* __restrict__ hin, int stride,
                            const float* __restrict__ Wp, float* __restrict__ P) {
  const int nt = blockIdx.x * 16;
  const int o = blockIdx.y * blockDim.x + threadIdx.x;
  __shared__ float hs[16][C];
  for (int i = threadIdx.x; i < 16 * C; i += blockDim.x) {
    int r = i / C, c = i - r * C;
    hs[r][c] = hin[(size_t)(nt + r) * stride + c];
  }
  __syncthreads();
  float acc[16];
#pragma unroll
  for (int t = 0; t < 16; t++) acc[t] = 0.0f;
  const float* wr = Wp + (size_t)o * C;
  if constexpr (C % 4 == 0) {
    for (int cg = 0; cg < C; cg += 4) {
      float4 w = *(const float4*)(wr + cg);
#pragma unroll
      for (int t = 0; t < 16; t++) {
        float4 h = *(const float4*)(&hs[t][cg]);
        acc[t] += w.x * h.x + w.y * h.y + w.z * h.z + w.w * h.w;
      }
    }
  } else {
    for (int c = 0; c < C; c++) {
      float w = wr[c];
#pragma unroll
      for (int t = 0; t < 16; t++) acc[t] += w * hs[t][c];
    }
  }
#pragma unroll
  for (int t = 0; t < 16; t++) P[(size_t)(nt + t) * O2 + o] = acc[t];
}

// h_out[row, o] = lrelu( max_k P[nbr_k, o] + P[row, O + o] + bias[o] ); also emits
// row norm (over this layer's O outputs) for the next layer's kNN.
template <int O>
__global__ void combine_kernel(const float* __restrict__ P, const int* __restrict__ idxo,
                               const float* __restrict__ bias, float* __restrict__ hout,
                               float* __restrict__ xxo) {
  const int row = blockIdx.x;
  const int o = threadIdx.x;
  __shared__ int idxs[K_];
  __shared__ float ps[4];
  if (o < K_) idxs[o] = idxo[(size_t)row * K_ + o];
  __syncthreads();
  const int base_row = (row >> 11) << 11;
  float g = -3.4e38f;
#pragma unroll
  for (int k = 0; k < K_; k++) {
    float v = P[(size_t)(base_row + idxs[k]) * (2 * O) + o];
    g = fmaxf(g, v);
  }
  float ba = P[(size_t)row * (2 * O) + O + o];
  float val = lrelu(g + ba + bias[o]);
  hout[(size_t)row * 512 + o] = val;
  if (xxo) {
    float sq = val * val;
#pragma unroll
    for (int off = 32; off > 0; off >>= 1) sq += __shfl_xor(sq, off, 64);
    if ((o & 63) == 0) ps[o >> 6] = sq;
    __syncthreads();
    if (o == 0) {
      float t = ps[0];
#pragma unroll
      for (int u = 1; u < O / 64; u++) t += ps[u];
      xxo[row] = t;
    }
  }
}

// Final GEMM: 128x128 tile, BK=32, global_load_lds(16B), 16x16x32 bf16 MFMA,
// epilogue = max over the block's 128 m-rows -> part.
__global__ __launch_bounds__(256) void gemm_final(const unsigned short* __restrict__ A,
                                                  const unsigned short* __restrict__ Bw,
                                                  float* __restrict__ part) {
  const int m0 = blockIdx.x * 128;
  const int n0 = blockIdx.y * 128;
  const int tid = threadIdx.x;
  const int w = tid >> 6, lane = tid & 63;
  const int wm = w & 1, wn = w >> 1;

  __shared__ unsigned short lA[128 * 32];
  __shared__ unsigned short lB[128 * 32];
  __shared__ float ldsred[2][128];

  const int r0 = (w * 2 + 0) * 16 + (lane >> 2);
  const int r1 = (w * 2 + 1) * 16 + (lane >> 2);
  const int ks = (lane & 3) * 8;
  const unsigned short* a0 = A + (size_t)(m0 + r0) * 512 + ks;
  const unsigned short* a1 = A + (size_t)(m0 + r1) * 512 + ks;
  const unsigned short* b0 = Bw + (size_t)(n0 + r0) * 512 + ks;
  const unsigned short* b1 = Bw + (size_t)(n0 + r1) * 512 + ks;
  unsigned short* lA0 = lA + (w * 2 + 0) * 512;
  unsigned short* lA1 = lA + (w * 2 + 1) * 512;
  unsigned short* lB0 = lB + (w * 2 + 0) * 512;
  unsigned short* lB1 = lB + (w * 2 + 1) * 512;

  f32x4 acc[4][4] = {};
  const int ka = (lane >> 4) * 8;

  for (int k0 = 0; k0 < 512; k0 += 32) {
    __syncthreads();
    async16(a0 + k0, lA0);
    async16(a1 + k0, lA1);
    async16(b0 + k0, lB0);
    async16(b1 + k0, lB1);
    __syncthreads();
    bf16x8 af[4], bfr[4];
#pragma unroll
    for (int mt = 0; mt < 4; mt++)
      af[mt] = *(const bf16x8*)&lA[(wm * 64 + mt * 16 + (lane & 15)) * 32 + ka];
#pragma unroll
    for (int nt = 0; nt < 4; nt++)
      bfr[nt] = *(const bf16x8*)&lB[(wn * 64 + nt * 16 + (lane & 15)) * 32 + ka];
#pragma unroll
    for (int mt = 0; mt < 4; mt++)
#pragma unroll
      for (int nt = 0; nt < 4; nt++)
        acc[mt][nt] = __builtin_amdgcn_mfma_f32_16x16x32_bf16(af[mt], bfr[nt], acc[mt][nt], 0, 0, 0);
  }

#pragma unroll
  for (int nt = 0; nt < 4; nt++) {
    float v = -3.4e38f;
#pragma unroll
    for (int mt = 0; mt < 4; mt++)
#pragma unroll
      for (int r = 0; r < 4; r++) v = fmaxf(v, acc[mt][nt][r]);
    v = fmaxf(v, __shfl_xor(v, 16, 64));
    v = fmaxf(v, __shfl_xor(v, 32, 64));
    if (lane < 16) ldsred[wm][wn * 64 + nt * 16 + lane] = v;
  }
  __syncthreads();
  if (tid < 128) {
    float v = fmaxf(ldsred[0][tid], ldsred[1][tid]);
    const int b = blockIdx.x >> 4, s5 = blockIdx.x & 15;
    part[(size_t)(b * 16 + s5) * 1024 + n0 + tid] = v;
  }
}

__global__ void final_reduce(const float* __restrict__ part, const float* __restrict__ bf,
                             float* __restrict__ out) {
  int i = blockIdx.x * 256 + threadIdx.x;
  if (i >= B_ * 1024) return;
  int b = i >> 10, o = i & 1023;
  float m = -3.4e38f;
  for (int s = 0; s < 16; s++) m = fmaxf(m, part[(size_t)(b * 16 + s) * 1024 + o]);
  out[i] = lrelu(m + bf[o]);
}

extern "C" void kernel_launch(void* const* d_in, const int* in_sizes, int n_in, void* d_out,
                              int out_size, void* d_ws, size_t ws_size, hipStream_t stream) {
  (void)in_sizes; (void)n_in; (void)out_size; (void)ws_size;
  const float* x = (const float*)d_in[0];
  const float* W1 = (const float*)d_in[1];
  const float* b1 = (const float*)d_in[2];
  const float* W2 = (const float*)d_in[3];
  const float* b2 = (const float*)d_in[4];
  const float* W3 = (const float*)d_in[5];
  const float* b3 = (const float*)d_in[6];
  const float* W4 = (const float*)d_in[7];
  const float* b4 = (const float*)d_in[8];
  const float* Wf = (const float*)d_in[9];
  const float* bf = (const float*)d_in[10];

  float* ws = (float*)d_ws;
  float* hcat = ws;                               // B*N*512 floats (32 MB)
  float* P = hcat + (size_t)B_ * N_ * 512;        // B*N*512 floats (32 MB)
  int* idx = (int*)(P + (size_t)B_ * N_ * 512);   // B*N*20 ints
  float* Wp = (float*)(idx + (size_t)B_ * N_ * K_);
  float* part = Wp + 512 * 128;                   // 8*16*1024 floats
  float* xxb = part + 8 * 16 * 1024;              // B*N floats (row norms)
  float* out = (float*)d_out;
  float* xT = P;                                  // alias P: xT dead before proj writes P
  unsigned short* hcat_bf = (unsigned short*)P;   // alias P (dead after layer-4)
  unsigned short* Wf_bf = hcat_bf + (size_t)B_ * N_ * 512;

  dim3 knng(N_ / 8, B_);
  dim3 trg(N_ / 64, B_);

  // Layer 1: C=3 -> O=64
  prep_wp<<<(2 * 64 * 3 + 255) / 256, 256, 0, stream>>>(W1, Wp, 64, 3);
  norms_x<<<(B_ * N_ + 255) / 256, 256, 0, stream>>>(x, xxb);
  transpose_feat<3, 4><<<trg, 256, 0, stream>>>(x, 3, xT);
  knn_kernel<3, 4><<<knng, 256, 0, stream>>>(x, 3, xT, xxb, idx);
  proj_kernel<3, 128><<<dim3(B_ * N_ / 16, 1), 128, 0, stream>>>(x, 3, Wp, P);
  combine_kernel<64><<<B_ * N_, 64, 0, stream>>>(P, idx, b1, hcat + 0, xxb);

  // Layer 2: C=64 -> O=64
  prep_wp<<<(2 * 64 * 64 + 255) / 256, 256, 0, stream>>>(W2, Wp, 64, 64);
  transpose_feat<64, 64><<<trg, 256, 0, stream>>>(hcat + 0, 512, xT);
  knn_kernel<64, 64><<<knng, 256, 0, stream>>>(hcat + 0, 512, xT, xxb, idx);
  proj_kernel<64, 128><<<dim3(B_ * N_ / 16, 1), 128, 0, stream>>>(hcat + 0, 512, Wp, P);
  combine_kernel<64><<<B_ * N_, 64, 0, stream>>>(P, idx, b2, hcat + 64, xxb);

  // Layer 3: C=64 -> O=128
  prep_wp<<<(2 * 128 * 64 + 255) / 256, 256, 0, stream>>>(W3, Wp, 128, 64);
  transpose_feat<64, 64><<<trg, 256, 0, stream>>>(hcat + 64, 512, xT);
  knn_kernel<64, 64><<<knng, 256, 0, stream>>>(hcat + 64, 512, xT, xxb, idx);
  proj_kernel<64, 256><<<dim3(B_ * N_ / 16, 1), 256, 0, stream>>>(hcat + 64, 512, Wp, P);
  combine_kernel<128><<<B_ * N_, 128, 0, stream>>>(P, idx, b3, hcat + 128, xxb);

  // Layer 4: C=128 -> O=256 (no norms needed afterwards)
  prep_wp<<<(2 * 256 * 128 + 255) / 256, 256, 0, stream>>>(W4, Wp, 256, 128);
  transpose_feat<128, 128><<<trg, 256, 0, stream>>>(hcat + 128, 512, xT);
  knn_kernel<128, 128><<<knng, 256, 0, stream>>>(hcat + 128, 512, xT, xxb, idx);
  proj_kernel<128, 512><<<dim3(B_ * N_ / 16, 2), 256, 0, stream>>>(hcat + 128, 512, Wp, P);
  combine_kernel<256><<<B_ * N_, 256, 0, stream>>>(P, idx, b4, hcat + 256, nullptr);

  // Final 1x1 conv via bf16 MFMA + fused max-over-rows
  cvt_bf16<<<(B_ * N_ * 512 / 4 + 255) / 256, 256, 0, stream>>>(
      (const float4*)hcat, (ushort4*)hcat_bf, B_ * N_ * 512 / 4);
  cvt_bf16<<<(1024 * 512 / 4 + 255) / 256, 256, 0, stream>>>(
      (const float4*)Wf, (ushort4*)Wf_bf, 1024 * 512 / 4);
  gemm_final<<<dim3(128, 8), 256, 0, stream>>>(hcat_bf, Wf_bf, part);
  final_reduce<<<(B_ * 1024 + 255) / 256, 256, 0, stream>>>(part, bf, out);
}

// Round 9
// 578.042 us; speedup vs baseline: 1.2495x; 1.1193x over previous
//
#include <hip/hip_runtime.h>

constexpr int B_ = 8;
constexpr int N_ = 2048;
constexpr int K_ = 20;
constexpr float SLOPE_ = 0.2f;

typedef __attribute__((ext_vector_type(8))) short bf16x8;
typedef __attribute__((ext_vector_type(4))) float f32x4;

__device__ __forceinline__ float lrelu(float v) { return v > 0.0f ? v : SLOPE_ * v; }

__device__ __forceinline__ void async16(const void* g, void* l) {
  __builtin_amdgcn_global_load_lds((const __attribute__((address_space(1))) unsigned int*)g,
                                   (__attribute__((address_space(3))) unsigned int*)l, 16, 0, 0);
}

__device__ __forceinline__ unsigned long long shflx64(unsigned long long v, int m) {
  return __shfl_xor(v, m, 64);
}

// Build Wp[2O x C]: rows [0,O) = Wd = W[:, :C]; rows [O,2O) = Wc - Wd
__global__ void prep_wp(const float* __restrict__ W, float* __restrict__ Wp, int O, int C) {
  int i = blockIdx.x * 256 + threadIdx.x;
  if (i >= 2 * O * C) return;
  int o = i / C, c = i - o * C;
  if (o < O)
    Wp[i] = W[o * 2 * C + c];
  else
    Wp[i] = W[(o - O) * 2 * C + C + c] - W[(o - O) * 2 * C + c];
}

// fp32 -> bf16 (RNE), vectorized x4
__global__ void cvt_bf16(const float4* __restrict__ src, ushort4* __restrict__ dst, int n4) {
  int i = blockIdx.x * 256 + threadIdx.x;
  if (i >= n4) return;
  float4 v = src[i];
  ushort4 o;
  unsigned u;
  u = __float_as_uint(v.x); u += 0x7fff + ((u >> 16) & 1); o.x = u >> 16;
  u = __float_as_uint(v.y); u += 0x7fff + ((u >> 16) & 1); o.y = u >> 16;
  u = __float_as_uint(v.z); u += 0x7fff + ((u >> 16) & 1); o.z = u >> 16;
  u = __float_as_uint(v.w); u += 0x7fff + ((u >> 16) & 1); o.w = u >> 16;
  dst[i] = o;
}

// norms of x rows (C=3)
__global__ void norms_x(const float* __restrict__ x, float* __restrict__ xx) {
  int i = blockIdx.x * 256 + threadIdx.x;
  if (i >= B_ * N_) return;
  const float* p = x + (size_t)i * 3;
  xx[i] = p[0] * p[0] + p[1] * p[1] + p[2] * p[2];
}

// Transpose features: hin rows (stride `stride`, C real cols) -> xT[b][CP][N_],
// zero-padding cols C..CP. LDS tile 64 rows x CP, both sides coalesced.
template <int C, int CP>
__global__ __launch_bounds__(256) void transpose_feat(const float* __restrict__ hin, int stride,
                                                      float* __restrict__ xT) {
  __shared__ float ts[64][CP + 1];
  const int b = blockIdx.y, n0 = blockIdx.x * 64;
  for (int i = threadIdx.x; i < 64 * C; i += 256) {
    int n = i / C, c = i - n * C;
    ts[n][c] = hin[(size_t)(b * N_ + n0 + n) * stride + c];
  }
  if (CP > C)
    for (int i = threadIdx.x; i < 64 * (CP - C); i += 256) {
      int n = i / (CP - C), c = C + (i - n * (CP - C));
      ts[n][c] = 0.0f;
    }
  __syncthreads();
  for (int i = threadIdx.x; i < 64 * CP; i += 256) {
    int c = i >> 6, n = i & 63;
    xT[((size_t)b * CP + c) * N_ + n0 + n] = ts[n][c];
  }
}

// kNN v8: 8 queries/block, 256 threads. NO LDS in the distance loop: each thread
// loads its 8 candidates (m = w*512 + lane*8 + j) straight from L2-resident xT as
// two coalesced float4 per k-slice (global->VGPR, compiler-managed vmcnt); query
// values are wave-uniform s_loads (scalar pipe, lgkmcnt). LDS pipe (per-CU, the
// R6/R8 bottleneck at VALUBusy~52%) is used only by the one-time exchange.
// Exchange: 2 rounds; writes are the canonical conflict-free b128 pattern
// (lane*16 B); wave w ends owning queries 2w,2w+1 with all 2048 candidates in regs.
//   r2[s][i]: m = mb(i) + lp,  mb(i) = ((i&15)>>2)*512 + (i&3... see code), lp =
//   (lane>>2)*8 + (lane&3). Value/index ordering identical to prior rounds.
// Selection: threshold (20th-smallest lane-min via bitonic) + ballot-compact + u64
// bitonic sort; exact-pop fallback if cnt > 64.
template <int C, int CP>
__global__ __launch_bounds__(256) void knn_kernel(const float* __restrict__ hin, int stride,
                                                  const float* __restrict__ xT,
                                                  const float* __restrict__ xx,
                                                  int* __restrict__ idxo) {
  const int b = blockIdx.y;
  const int q0 = blockIdx.x * 8;
  const int tid = threadIdx.x;
  const int w = tid >> 6, lane = tid & 63;
  const int bN = b * N_;

  __shared__ float d2s[8][1024];             // exchange buffer (32 KB)
  __shared__ unsigned long long cbuf[4][64];  // per-wave compact buffers (2 KB)

  const float* qrow0 = hin + (size_t)(bN + q0) * stride;  // wave-uniform -> s_load

  float acc[8][8] = {};  // [q][j], m = w*512 + lane*8 + j
  const float* xcol = xT + (size_t)b * CP * N_ + w * 512 + lane * 8;

#pragma unroll 4
  for (int c = 0; c < CP; c++) {
    float4 x0 = *(const float4*)(xcol + (size_t)c * N_);
    float4 x1 = *(const float4*)(xcol + (size_t)c * N_ + 4);
    float xv[8] = {x0.x, x0.y, x0.z, x0.w, x1.x, x1.y, x1.z, x1.w};
#pragma unroll
    for (int q = 0; q < 8; q++) {
      float qv;
      if constexpr (CP == C)
        qv = qrow0[(size_t)q * stride + c];
      else
        qv = (c < C) ? qrow0[(size_t)q * stride + c] : 0.0f;
#pragma unroll
      for (int j = 0; j < 8; j++) acc[q][j] = fmaf(xv[j], qv, acc[q][j]);
    }
  }

  // d2 = max(xx_m + xx_q - 2*dot, 0)
  float4 xm0 = *(const float4*)(xx + bN + w * 512 + lane * 8);
  float4 xm1 = *(const float4*)(xx + bN + w * 512 + lane * 8 + 4);
  float xxm[8] = {xm0.x, xm0.y, xm0.z, xm0.w, xm1.x, xm1.y, xm1.z, xm1.w};
  float qnr[8];
#pragma unroll
  for (int q = 0; q < 8; q++) qnr[q] = xx[bN + q0 + q];  // uniform -> s_load
#pragma unroll
  for (int q = 0; q < 8; q++)
#pragma unroll
    for (int j = 0; j < 8; j++)
      acc[q][j] = fmaxf(fmaf(-2.0f, acc[q][j], xxm[j] + qnr[q]), 0.0f);

  // exchange: round jc moves j-half {4jc..4jc+3}. Writes: b128, lane-contiguous
  // 16B (conflict-free). Reads: b32 conflict-free.
  float r2[2][32];
#pragma unroll
  for (int jc = 0; jc < 2; jc++) {
    __syncthreads();
#pragma unroll
    for (int q = 0; q < 8; q++) {
      float4 v = {acc[q][jc * 4 + 0], acc[q][jc * 4 + 1], acc[q][jc * 4 + 2],
                  acc[q][jc * 4 + 3]};
      *(float4*)&d2s[q][w * 256 + lane * 4] = v;
    }
    __syncthreads();
#pragma unroll
    for (int s = 0; s < 2; s++)
#pragma unroll
      for (int t = 0; t < 16; t++) r2[s][jc * 16 + t] = d2s[2 * w + s][t * 64 + lane];
  }

  const float INF = __int_as_float(0x7f800000);
  const int lp = (lane >> 2) * 8 + (lane & 3);  // lane's m-offset within mb(i)
  unsigned long long* cb = cbuf[w];

#pragma unroll
  for (int s = 0; s < 2; s++) {
    const int q = 2 * w + s;
    int* outp = idxo + (size_t)(bN + q0 + q) * K_;

    // ---- threshold: T = 20th-smallest per-lane min ----
    float lmin = r2[s][0];
#pragma unroll
    for (int i = 1; i < 32; i++) lmin = fminf(lmin, r2[s][i]);
    float sv = lmin;
#pragma unroll
    for (int k = 2; k <= 64; k <<= 1)
#pragma unroll
      for (int j = k >> 1; j > 0; j >>= 1) {
        float p = __shfl_xor(sv, j, 64);
        bool takeMax = ((lane & j) != 0) == ((lane & k) == 0);
        sv = takeMax ? fmaxf(sv, p) : fminf(sv, p);
      }
    float T = __shfl(sv, 19, 64);

    // ---- count + compact candidates <= T ----
    unsigned cnt = 0;
#pragma unroll
    for (int i = 0; i < 32; i++) {
      const int t = i & 15;
      const int mb = (t >> 2) * 512 + (t & 3) * 128 + (i >> 4) * 4;
      bool pred = r2[s][i] <= T;
      unsigned long long mk = __ballot(pred);
      if (mk) {
        int off = __popcll(mk & ((1ull << lane) - 1ull));
        unsigned pos = cnt + (unsigned)off;
        if (pred && pos < 64)
          cb[pos] = ((unsigned long long)__float_as_uint(r2[s][i]) << 32) | (unsigned)(mb + lp);
        cnt += (unsigned)__popcll(mk);
      }
    }

    if (cnt <= 64) {
      unsigned long long v = (lane < (int)cnt) ? cb[lane] : ~0ull;
#pragma unroll
      for (int k = 2; k <= 64; k <<= 1)
#pragma unroll
        for (int j = k >> 1; j > 0; j >>= 1) {
          unsigned long long p = shflx64(v, j);
          bool takeMax = ((lane & j) != 0) == ((lane & k) == 0);
          bool lt = v < p;
          v = (takeMax == lt) ? p : v;
        }
      if (lane < K_) outp[lane] = (int)(unsigned)(v & 0xffffffffull);
    } else {
      for (int t2 = 0; t2 < K_; t2++) {
        unsigned long long loc = ~0ull;
#pragma unroll
        for (int i = 0; i < 32; i++) {
          const int t = i & 15;
          const int mb = (t >> 2) * 512 + (t & 3) * 128 + (i >> 4) * 4;
          unsigned long long u =
              ((unsigned long long)__float_as_uint(r2[s][i]) << 32) | (unsigned)(mb + lp);
          loc = u < loc ? u : loc;
        }
#pragma unroll
        for (int off = 32; off > 0; off >>= 1) {
          unsigned long long vv = shflx64(loc, off);
          loc = vv < loc ? vv : loc;
        }
        const int mwin = (int)(unsigned)(loc & 0xffffffffull);
        if (lane == 0) outp[t2] = mwin;
#pragma unroll
        for (int i = 0; i < 32; i++) {
          const int t = i & 15;
          const int mb = (t >> 2) * 512 + (t & 3) * 128 + (i >> 4) * 4;
          if (mb + lp == mwin) r2[s][i] = INF;
        }
      }
    }
  }
}

// P[row, o'] = sum_c h[row, c] * Wp[o', c]   for o' in [0, 2O)  (R5 version)
template <int C, int O2>
__global__ void proj_kernel(const float* __restrict__ hin, int stride,
                            const float* __restrict__ Wp, float* __restrict__ P) {
  const int nt = blockIdx.x * 16;
  const int o = blockIdx.y * blockDim.x + threadIdx.x;
  __shared__ float hs[16][C];
  for (int i = threadIdx.x; i < 16 * C; i += blockDim.x) {
    int r = i / C, c = i - r * C;
    hs[r][c] = hin[(size_t)(nt + r) * stride + c];
  }
  __syncthreads();
  float acc[16];
#pragma unroll
  for (int t = 0; t < 16; t++) acc[t] = 0.0f;
  const float* wr = Wp + (size_t)o * C;
  if constexpr (C % 4 == 0) {
    for (int cg = 0; cg < C; cg += 4) {
      float4 w = *(const float4*)(wr + cg);
#pragma unroll
      for (int t = 0; t < 16; t++) {
        float4 h = *(const float4*)(&hs[t][cg]);
        acc[t] += w.x * h.x + w.y * h.y + w.z * h.z + w.w * h.w;
      }
    }
  } else {
    for (int c = 0; c < C; c++) {
      float w = wr[c];
#pragma unroll
      for (int t = 0; t < 16; t++) acc[t] += w * hs[t][c];
    }
  }
#pragma unroll
  for (int t = 0; t < 16; t++) P[(size_t)(nt + t) * O2 + o] = acc[t];
}

// h_out[row, o] = lrelu( max_k P[nbr_k, o] + P[row, O + o] + bias[o] ); also emits
// row norm (over this layer's O outputs) for the next layer's kNN.
template <int O>
__global__ void combine_kernel(const float* __restrict__ P, const int* __restrict__ idxo,
                               const float* __restrict__ bias, float* __restrict__ hout,
                               float* __restrict__ xxo) {
  const int row = blockIdx.x;
  const int o = threadIdx.x;
  __shared__ int idxs[K_];
  __shared__ float ps[4];
  if (o < K_) idxs[o] = idxo[(size_t)row * K_ + o];
  __syncthreads();
  const int base_row = (row >> 11) << 11;
  float g = -3.4e38f;
#pragma unroll
  for (int k = 0; k < K_; k++) {
    float v = P[(size_t)(base_row + idxs[k]) * (2 * O) + o];
    g = fmaxf(g, v);
  }
  float ba = P[(size_t)row * (2 * O) + O + o];
  float val = lrelu(g + ba + bias[o]);
  hout[(size_t)row * 512 + o] = val;
  if (xxo) {
    float sq = val * val;
#pragma unroll
    for (int off = 32; off > 0; off >>= 1) sq += __shfl_xor(sq, off, 64);
    if ((o & 63) == 0) ps[o >> 6] = sq;
    __syncthreads();
    if (o == 0) {
      float t = ps[0];
#pragma unroll
      for (int u = 1; u < O / 64; u++) t += ps[u];
      xxo[row] = t;
    }
  }
}

// Final GEMM: 128x128 tile, BK=32, global_load_lds(16B), 16x16x32 bf16 MFMA,
// epilogue = max over the block's 128 m-rows -> part.
__global__ __launch_bounds__(256) void gemm_final(const unsigned short* __restrict__ A,
                                                  const unsigned short* __restrict__ Bw,
                                                  float* __restrict__ part) {
  const int m0 = blockIdx.x * 128;
  const int n0 = blockIdx.y * 128;
  const int tid = threadIdx.x;
  const int w = tid >> 6, lane = tid & 63;
  const int wm = w & 1, wn = w >> 1;

  __shared__ unsigned short lA[128 * 32];
  __shared__ unsigned short lB[128 * 32];
  __shared__ float ldsred[2][128];

  const int r0 = (w * 2 + 0) * 16 + (lane >> 2);
  const int r1 = (w * 2 + 1) * 16 + (lane >> 2);
  const int ks = (lane & 3) * 8;
  const unsigned short* a0 = A + (size_t)(m0 + r0) * 512 + ks;
  const unsigned short* a1 = A + (size_t)(m0 + r1) * 512 + ks;
  const unsigned short* b0 = Bw + (size_t)(n0 + r0) * 512 + ks;
  const unsigned short* b1 = Bw + (size_t)(n0 + r1) * 512 + ks;
  unsigned short* lA0 = lA + (w * 2 + 0) * 512;
  unsigned short* lA1 = lA + (w * 2 + 1) * 512;
  unsigned short* lB0 = lB + (w * 2 + 0) * 512;
  unsigned short* lB1 = lB + (w * 2 + 1) * 512;

  f32x4 acc[4][4] = {};
  const int ka = (lane >> 4) * 8;

  for (int k0 = 0; k0 < 512; k0 += 32) {
    __syncthreads();
    async16(a0 + k0, lA0);
    async16(a1 + k0, lA1);
    async16(b0 + k0, lB0);
    async16(b1 + k0, lB1);
    __syncthreads();
    bf16x8 af[4], bfr[4];
#pragma unroll
    for (int mt = 0; mt < 4; mt++)
      af[mt] = *(const bf16x8*)&lA[(wm * 64 + mt * 16 + (lane & 15)) * 32 + ka];
#pragma unroll
    for (int nt = 0; nt < 4; nt++)
      bfr[nt] = *(const bf16x8*)&lB[(wn * 64 + nt * 16 + (lane & 15)) * 32 + ka];
#pragma unroll
    for (int mt = 0; mt < 4; mt++)
#pragma unroll
      for (int nt = 0; nt < 4; nt++)
        acc[mt][nt] = __builtin_amdgcn_mfma_f32_16x16x32_bf16(af[mt], bfr[nt], acc[mt][nt], 0, 0, 0);
  }

#pragma unroll
  for (int nt = 0; nt < 4; nt++) {
    float v = -3.4e38f;
#pragma unroll
    for (int mt = 0; mt < 4; mt++)
#pragma unroll
      for (int r = 0; r < 4; r++) v = fmaxf(v, acc[mt][nt][r]);
    v = fmaxf(v, __shfl_xor(v, 16, 64));
    v = fmaxf(v, __shfl_xor(v, 32, 64));
    if (lane < 16) ldsred[wm][wn * 64 + nt * 16 + lane] = v;
  }
  __syncthreads();
  if (tid < 128) {
    float v = fmaxf(ldsred[0][tid], ldsred[1][tid]);
    const int b = blockIdx.x >> 4, s5 = blockIdx.x & 15;
    part[(size_t)(b * 16 + s5) * 1024 + n0 + tid] = v;
  }
}

__global__ void final_reduce(const float* __restrict__ part, const float* __restrict__ bf,
                             float* __restrict__ out) {
  int i = blockIdx.x * 256 + threadIdx.x;
  if (i >= B_ * 1024) return;
  int b = i >> 10, o = i & 1023;
  float m = -3.4e38f;
  for (int s = 0; s < 16; s++) m = fmaxf(m, part[(size_t)(b * 16 + s) * 1024 + o]);
  out[i] = lrelu(m + bf[o]);
}

extern "C" void kernel_launch(void* const* d_in, const int* in_sizes, int n_in, void* d_out,
                              int out_size, void* d_ws, size_t ws_size, hipStream_t stream) {
  (void)in_sizes; (void)n_in; (void)out_size; (void)ws_size;
  const float* x = (const float*)d_in[0];
  const float* W1 = (const float*)d_in[1];
  const float* b1 = (const float*)d_in[2];
  const float* W2 = (const float*)d_in[3];
  const float* b2 = (const float*)d_in[4];
  const float* W3 = (const float*)d_in[5];
  const float* b3 = (const float*)d_in[6];
  const float* W4 = (const float*)d_in[7];
  const float* b4 = (const float*)d_in[8];
  const float* Wf = (const float*)d_in[9];
  const float* bf = (const float*)d_in[10];

  float* ws = (float*)d_ws;
  float* hcat = ws;                               // B*N*512 floats (32 MB)
  float* P = hcat + (size_t)B_ * N_ * 512;        // B*N*512 floats (32 MB)
  int* idx = (int*)(P + (size_t)B_ * N_ * 512);   // B*N*20 ints
  float* Wp = (float*)(idx + (size_t)B_ * N_ * K_);
  float* part = Wp + 512 * 128;                   // 8*16*1024 floats
  float* xxb = part + 8 * 16 * 1024;              // B*N floats (row norms)
  float* out = (float*)d_out;
  float* xT = P;                                  // alias P: xT dead before proj writes P
  unsigned short* hcat_bf = (unsigned short*)P;   // alias P (dead after layer-4)
  unsigned short* Wf_bf = hcat_bf + (size_t)B_ * N_ * 512;

  dim3 knng(N_ / 8, B_);
  dim3 trg(N_ / 64, B_);

  // Layer 1: C=3 -> O=64
  prep_wp<<<(2 * 64 * 3 + 255) / 256, 256, 0, stream>>>(W1, Wp, 64, 3);
  norms_x<<<(B_ * N_ + 255) / 256, 256, 0, stream>>>(x, xxb);
  transpose_feat<3, 4><<<trg, 256, 0, stream>>>(x, 3, xT);
  knn_kernel<3, 4><<<knng, 256, 0, stream>>>(x, 3, xT, xxb, idx);
  proj_kernel<3, 128><<<dim3(B_ * N_ / 16, 1), 128, 0, stream>>>(x, 3, Wp, P);
  combine_kernel<64><<<B_ * N_, 64, 0, stream>>>(P, idx, b1, hcat + 0, xxb);

  // Layer 2: C=64 -> O=64
  prep_wp<<<(2 * 64 * 64 + 255) / 256, 256, 0, stream>>>(W2, Wp, 64, 64);
  transpose_feat<64, 64><<<trg, 256, 0, stream>>>(hcat + 0, 512, xT);
  knn_kernel<64, 64><<<knng, 256, 0, stream>>>(hcat + 0, 512, xT, xxb, idx);
  proj_kernel<64, 128><<<dim3(B_ * N_ / 16, 1), 128, 0, stream>>>(hcat + 0, 512, Wp, P);
  combine_kernel<64><<<B_ * N_, 64, 0, stream>>>(P, idx, b2, hcat + 64, xxb);

  // Layer 3: C=64 -> O=128
  prep_wp<<<(2 * 128 * 64 + 255) / 256, 256, 0, stream>>>(W3, Wp, 128, 64);
  transpose_feat<64, 64><<<trg, 256, 0, stream>>>(hcat + 64, 512, xT);
  knn_kernel<64, 64><<<knng, 256, 0, stream>>>(hcat + 64, 512, xT, xxb, idx);
  proj_kernel<64, 256><<<dim3(B_ * N_ / 16, 1), 256, 0, stream>>>(hcat + 64, 512, Wp, P);
  combine_kernel<128><<<B_ * N_, 128, 0, stream>>>(P, idx, b3, hcat + 128, xxb);

  // Layer 4: C=128 -> O=256 (no norms needed afterwards)
  prep_wp<<<(2 * 256 * 128 + 255) / 256, 256, 0, stream>>>(W4, Wp, 256, 128);
  transpose_feat<128, 128><<<trg, 256, 0, stream>>>(hcat + 128, 512, xT);
  knn_kernel<128, 128><<<knng, 256, 0, stream>>>(hcat + 128, 512, xT, xxb, idx);
  proj_kernel<128, 512><<<dim3(B_ * N_ / 16, 2), 256, 0, stream>>>(hcat + 128, 512, Wp, P);
  combine_kernel<256><<<B_ * N_, 256, 0, stream>>>(P, idx, b4, hcat + 256, nullptr);

  // Final 1x1 conv via bf16 MFMA + fused max-over-rows
  cvt_bf16<<<(B_ * N_ * 512 / 4 + 255) / 256, 256, 0, stream>>>(
      (const float4*)hcat, (ushort4*)hcat_bf, B_ * N_ * 512 / 4);
  cvt_bf16<<<(1024 * 512 / 4 + 255) / 256, 256, 0, stream>>>(
      (const float4*)Wf, (ushort4*)Wf_bf, 1024 * 512 / 4);
  gemm_final<<<dim3(128, 8), 256, 0, stream>>>(hcat_bf, Wf_bf, part);
  final_reduce<<<(B_ * 1024 + 255) / 256, 256, 0, stream>>>(part, bf, out);
}